// Round 6
// baseline (223.291 us; speedup 1.0000x reference)
//
#include <hip/hip_runtime.h>
#include <hip/hip_bf16.h>
#include <stdint.h>

#define D_MODEL 1024
#define NHEADS  16
#define DKH     64
#define BATCH   2
#define SEQ     2048
#define MTOT    (BATCH*SEQ)   // 4096

typedef __attribute__((ext_vector_type(8))) short bf16x8;   // 8 bf16 = 4 VGPRs
typedef __attribute__((ext_vector_type(4))) float f32x4;

__device__ inline unsigned short f2bf(float f) {
    __hip_bfloat16 h = __float2bfloat16(f);
    return *reinterpret_cast<unsigned short*>(&h);
}

// async global->LDS, 16B per lane; LDS dest = wave-uniform base + lane*16 (m97/m104)
__device__ inline void gl2lds16(const unsigned short* g, unsigned short* l) {
    __builtin_amdgcn_global_load_lds(
        (const __attribute__((address_space(1))) void*)g,
        (__attribute__((address_space(3))) void*)l,
        16, 0, 0);
}

// One-shot fp32 -> bf16 conversion of x and the 4 weight matrices.
__global__ __launch_bounds__(256) void cvt_all(
    const float* __restrict__ x,  const float* __restrict__ wq,
    const float* __restrict__ wk, const float* __restrict__ wv,
    const float* __restrict__ wo,
    unsigned short* __restrict__ xb,  unsigned short* __restrict__ wqb,
    unsigned short* __restrict__ wkb, unsigned short* __restrict__ wvb,
    unsigned short* __restrict__ wob)
{
    int bid = blockIdx.x;
    const float* s; unsigned short* d; size_t base;
    if (bid < 2048) { s = x; d = xb; base = (size_t)bid * 2048; }
    else {
        int w  = (bid - 2048) >> 9;
        int wb = (bid - 2048) & 511;
        s = (w == 0) ? wq : (w == 1) ? wk : (w == 2) ? wv : wo;
        d = (w == 0) ? wqb : (w == 1) ? wkb : (w == 2) ? wvb : wob;
        base = (size_t)wb * 2048;
    }
    size_t i = base + (size_t)threadIdx.x * 8;
    float4 a = *(const float4*)(s + i);
    float4 b = *(const float4*)(s + i + 4);
    unsigned short t8[8] = {f2bf(a.x), f2bf(a.y), f2bf(a.z), f2bf(a.w),
                            f2bf(b.x), f2bf(b.y), f2bf(b.z), f2bf(b.w)};
    *(uint4*)(d + i) = *(uint4*)t8;
}

// Vb (MTOT, D_MODEL) bf16 -> VtG [(b*16+h)*64+dk][s] via LDS tile.
__global__ __launch_bounds__(256) void vtrans_kernel(
    const unsigned short* __restrict__ Vb, unsigned short* __restrict__ VtG)
{
    __shared__ __align__(16) unsigned short T[64 * 72];
    const int st = blockIdx.x;
    const int bh = blockIdx.y;
    const int b  = bh >> 4, h = bh & 15;
    const int t  = threadIdx.x;
    const int r  = t >> 2, c = (t & 3) * 16;

    const unsigned short* src = Vb + (size_t)(b * SEQ + st * 64 + r) * D_MODEL + h * DKH + c;
    *(uint4*)(T + r * 72 + c)     = *(const uint4*)(src);
    *(uint4*)(T + r * 72 + c + 8) = *(const uint4*)(src + 8);
    __syncthreads();

    unsigned short tmp[16];
    #pragma unroll
    for (int i = 0; i < 16; ++i) tmp[i] = T[(c + i) * 72 + r];
    unsigned short* dst = VtG + (size_t)(bh * DKH + r) * SEQ + st * 64 + c;
    *(uint4*)(dst)     = *(uint4*)tmp;
    *(uint4*)(dst + 8) = *(uint4*)(tmp + 8);
}

// C[M,N] = scale * A[M,K] @ W[N,K]^T ; bf16 in, fp32 accum, C bf16 or fp32.
// BK=64 as two m97-style BK=32 sub-tiles (unpadded 128x32, global_load_lds w=16).
template<bool CF32>
__global__ __launch_bounds__(256) void gemm_bt(
    const unsigned short* __restrict__ A,
    const unsigned short* __restrict__ W0,
    const unsigned short* __restrict__ W1,
    const unsigned short* __restrict__ W2,
    void* __restrict__ C0, void* __restrict__ C1, void* __restrict__ C2,
    int M, int N, int K, float scale0)
{
    const unsigned short* W = (blockIdx.z == 0) ? W0 : (blockIdx.z == 1 ? W1 : W2);
    void*                 C = (blockIdx.z == 0) ? C0 : (blockIdx.z == 1 ? C1 : C2);
    const float scl = (blockIdx.z == 0) ? scale0 : 1.0f;

    // two BK=32 sub-tiles each, unpadded [128][32] (m97 layout -> conflict-free)
    __shared__ __align__(16) unsigned short As[2][128 * 32];
    __shared__ __align__(16) unsigned short Bs[2][128 * 32];

    const int t    = threadIdx.x;
    const int wave = t >> 6, lane = t & 63;
    const int quad = lane >> 4, l16 = lane & 15;
    const int wm   = (wave >> 1) * 64, wn = (wave & 1) * 64;
    const int m0   = blockIdx.x * 128, n0 = blockIdx.y * 128;

    // m97 staging: wave w covers rows [w*32, w*32+32) of each sub-tile,
    // two 1KB instrs of 16 rows; lane -> row w*32 + lane/4, 16B chunk lane%4.
    const int srow = lane >> 2;
    const int schk = (lane & 3) * 8;   // shorts
    const unsigned short* Ag = A + (size_t)(m0 + wave * 32 + srow) * K + schk;
    const unsigned short* Wg = W + (size_t)(n0 + wave * 32 + srow) * K + schk;
    const size_t rstep = (size_t)16 * K;
    unsigned short* AsB0 = &As[0][0] + wave * 1024;   // wave-uniform LDS bases
    unsigned short* BsB0 = &Bs[0][0] + wave * 1024;

    f32x4 acc[4][4] = {};

    for (int k0 = 0; k0 < K; k0 += 64) {
        __syncthreads();               // prior frag reads done before overwrite
        #pragma unroll
        for (int s = 0; s < 2; ++s) {
            gl2lds16(Ag + k0 + s * 32,         AsB0 + s * 4096);
            gl2lds16(Ag + k0 + s * 32 + rstep, AsB0 + s * 4096 + 512);
            gl2lds16(Wg + k0 + s * 32,         BsB0 + s * 4096);
            gl2lds16(Wg + k0 + s * 32 + rstep, BsB0 + s * 4096 + 512);
        }
        __syncthreads();               // drains vmcnt: LDS tiles complete

        #pragma unroll
        for (int s = 0; s < 2; ++s) {
            bf16x8 afr[4], bfr[4];
            #pragma unroll
            for (int i = 0; i < 4; ++i) {
                afr[i] = *(const bf16x8*)(&As[s][0] + (wm + i * 16 + l16) * 32 + quad * 8);
                bfr[i] = *(const bf16x8*)(&Bs[s][0] + (wn + i * 16 + l16) * 32 + quad * 8);
            }
            #pragma unroll
            for (int i = 0; i < 4; ++i)
                #pragma unroll
                for (int j = 0; j < 4; ++j)
                    acc[i][j] = __builtin_amdgcn_mfma_f32_16x16x32_bf16(afr[i], bfr[j], acc[i][j], 0, 0, 0);
        }
    }

    #pragma unroll
    for (int i = 0; i < 4; ++i)
        #pragma unroll
        for (int j = 0; j < 4; ++j)
            #pragma unroll
            for (int r = 0; r < 4; ++r) {
                int row = m0 + wm + i * 16 + quad * 4 + r;
                int col = n0 + wn + j * 16 + l16;
                float v = acc[i][j][r] * scl;
                if (CF32) ((float*)C)[(size_t)row * N + col] = v;
                else      ((unsigned short*)C)[(size_t)row * N + col] = f2bf(v);
            }
}

// Flash causal attention, fixed-m softmax, l via ones-column MFMA.
// Q-block = 128 rows; wave w computes bands {w*16, 64+w*16} (2x MFMA per LDS read).
// K/V double-buffered in LDS -> ONE barrier per k-iter, global prefetch overlaps.
// grid (32=b*h, 16=q128 heavy-first), block 256.
__global__ __launch_bounds__(256) void attn_kernel(
    const unsigned short* __restrict__ Qm,
    const unsigned short* __restrict__ Km,
    const unsigned short* __restrict__ VtG,
    unsigned short* __restrict__ Om)
{
    const int bh  = blockIdx.x;
    const int qt2 = 15 - blockIdx.y;            // heavy tiles first (LPT)
    const int h = bh & 15, b = bh >> 4;
    const int t    = threadIdx.x;
    const int wave = t >> 6, lane = t & 63;
    const int quad = lane >> 4, l16 = lane & 15;

    __shared__ __align__(16) unsigned short Ks[2][64 * 72];
    __shared__ __align__(16) unsigned short Vt[2][64 * 72];
    __shared__ __align__(16) unsigned short Ps[4][16 * 68];

    const size_t base = (size_t)b * SEQ * D_MODEL + (size_t)h * DKH;
    const unsigned short* Qh = Qm + base;
    const unsigned short* Kh = Km + base;
    const unsigned short* Vh = VtG + (size_t)bh * DKH * SEQ;   // [dk][s]

    // Q A-frags for both bands (Q pre-scaled by 1/8 in projection)
    bf16x8 qf[2][2];
    #pragma unroll
    for (int b2 = 0; b2 < 2; ++b2) {
        const int qrow = qt2 * 128 + b2 * 64 + wave * 16 + l16;
        qf[b2][0] = *(const bf16x8*)(Qh + (size_t)qrow * D_MODEL + quad * 8);
        qf[b2][1] = *(const bf16x8*)(Qh + (size_t)qrow * D_MODEL + 32 + quad * 8);
    }

    bf16x8 onesf;
    {
        short ov = (l16 == 0) ? (short)0x3F80 : (short)0;
        #pragma unroll
        for (int j = 0; j < 8; ++j) onesf[j] = ov;
    }

    f32x4 accO[2][4] = {};
    f32x4 accL[2] = {};

    const int srow = t >> 2, scol = (t & 3) * 16;
    const int ktiles = 2 * qt2 + 2;

    // preload tile 0 -> regs -> buf 0
    uint4 kr0, kr1, vr0, vr1;
    {
        const unsigned short* ks = Kh + (size_t)srow * D_MODEL + scol;
        kr0 = *(const uint4*)ks; kr1 = *(const uint4*)(ks + 8);
        const unsigned short* vs = Vh + (size_t)srow * SEQ + scol;
        vr0 = *(const uint4*)vs; vr1 = *(const uint4*)(vs + 8);
    }
    *(uint4*)(&Ks[0][0] + srow * 72 + scol)     = kr0;
    *(uint4*)(&Ks[0][0] + srow * 72 + scol + 8) = kr1;
    *(uint4*)(&Vt[0][0] + srow * 72 + scol)     = vr0;
    *(uint4*)(&Vt[0][0] + srow * 72 + scol + 8) = vr1;
    __syncthreads();

    for (int kt = 0; kt < ktiles; ++kt) {
        const int cur = kt & 1, nxt = cur ^ 1;
        const bool more = (kt + 1 < ktiles);

        if (more) {    // global prefetch of tile kt+1; latency hidden by compute
            const unsigned short* ks = Kh + (size_t)((kt + 1) * 64 + srow) * D_MODEL + scol;
            kr0 = *(const uint4*)ks; kr1 = *(const uint4*)(ks + 8);
            const unsigned short* vs = Vh + (size_t)srow * SEQ + (kt + 1) * 64 + scol;
            vr0 = *(const uint4*)vs; vr1 = *(const uint4*)(vs + 8);
        }

        const bool band0 = (kt <= 2 * qt2);           // band0 done before last tile
        const bool diag0 = (kt == 2 * qt2);
        const bool diag1 = (kt == 2 * qt2 + 1);

        // S = Q K^T ; each kf read feeds both bands
        f32x4 s0[4] = {}, s1[4] = {};
        #pragma unroll
        for (int nb = 0; nb < 4; ++nb)
            #pragma unroll
            for (int ks = 0; ks < 2; ++ks) {
                bf16x8 kf = *(const bf16x8*)(&Ks[cur][0] + (nb * 16 + l16) * 72 + ks * 32 + quad * 8);
                if (band0) s0[nb] = __builtin_amdgcn_mfma_f32_16x16x32_bf16(qf[0][ks], kf, s0[nb], 0, 0, 0);
                s1[nb] = __builtin_amdgcn_mfma_f32_16x16x32_bf16(qf[1][ks], kf, s1[nb], 0, 0, 0);
            }

        const int lrow = wave * 16 + quad * 4;        // local row within band
        unsigned short* Pw = &Ps[wave][0];
        bf16x8 pf0[2], pf1[2];

        if (band0) {
            #pragma unroll
            for (int nb = 0; nb < 4; ++nb)
                #pragma unroll
                for (int r = 0; r < 4; ++r) {
                    float v = s0[nb][r];
                    if (diag0) v = (nb * 16 + l16 <= lrow + r) ? v : -1e30f;
                    Pw[(quad * 4 + r) * 68 + nb * 16 + l16] = f2bf(__expf(v));
                }
            __builtin_amdgcn_s_waitcnt(0xC07F);       // lgkmcnt(0); Ps wave-private
            pf0[0] = *(const bf16x8*)(Pw + l16 * 68 + quad * 8);
            pf0[1] = *(const bf16x8*)(Pw + l16 * 68 + 32 + quad * 8);
        }
        {
            #pragma unroll
            for (int nb = 0; nb < 4; ++nb)
                #pragma unroll
                for (int r = 0; r < 4; ++r) {
                    float v = s1[nb][r];
                    if (diag1) v = (nb * 16 + l16 <= lrow + r) ? v : -1e30f;
                    Pw[(quad * 4 + r) * 68 + nb * 16 + l16] = f2bf(__expf(v));
                }
            __builtin_amdgcn_s_waitcnt(0xC07F);
            pf1[0] = *(const bf16x8*)(Pw + l16 * 68 + quad * 8);
            pf1[1] = *(const bf16x8*)(Pw + l16 * 68 + 32 + quad * 8);
        }

        // O += P V ; each vf read feeds both bands
        #pragma unroll
        for (int db = 0; db < 4; ++db)
            #pragma unroll
            for (int ks = 0; ks < 2; ++ks) {
                bf16x8 vf = *(const bf16x8*)(&Vt[cur][0] + (db * 16 + l16) * 72 + ks * 32 + quad * 8);
                if (band0) accO[0][db] = __builtin_amdgcn_mfma_f32_16x16x32_bf16(pf0[ks], vf, accO[0][db], 0, 0, 0);
                accO[1][db] = __builtin_amdgcn_mfma_f32_16x16x32_bf16(pf1[ks], vf, accO[1][db], 0, 0, 0);
            }
        if (band0) {
            accL[0] = __builtin_amdgcn_mfma_f32_16x16x32_bf16(pf0[0], onesf, accL[0], 0, 0, 0);
            accL[0] = __builtin_amdgcn_mfma_f32_16x16x32_bf16(pf0[1], onesf, accL[0], 0, 0, 0);
        }
        accL[1] = __builtin_amdgcn_mfma_f32_16x16x32_bf16(pf1[0], onesf, accL[1], 0, 0, 0);
        accL[1] = __builtin_amdgcn_mfma_f32_16x16x32_bf16(pf1[1], onesf, accL[1], 0, 0, 0);

        if (more) {   // write prefetched tile into the other buffer (read in kt-1, safe)
            *(uint4*)(&Ks[nxt][0] + srow * 72 + scol)     = kr0;
            *(uint4*)(&Ks[nxt][0] + srow * 72 + scol + 8) = kr1;
            *(uint4*)(&Vt[nxt][0] + srow * 72 + scol)     = vr0;
            *(uint4*)(&Vt[nxt][0] + srow * 72 + scol + 8) = vr1;
            __syncthreads();   // single barrier per iter (block-uniform condition)
        }
    }

    // epilogue: l broadcast (col0 -> quad), divide, store merged (b,l,h*64+dk)
    #pragma unroll
    for (int b2 = 0; b2 < 2; ++b2) {
        const int orow0 = b * SEQ + qt2 * 128 + b2 * 64 + wave * 16 + quad * 4;
        const int ocol0 = h * DKH + l16;
        #pragma unroll
        for (int r = 0; r < 4; ++r) {
            float l_r = __shfl(accL[b2][r], (lane & 48), 64);   // src lane = quad*16
            float inv = 1.f / l_r;
            #pragma unroll
            for (int db = 0; db < 4; ++db)
                Om[(size_t)(orow0 + r) * D_MODEL + ocol0 + db * 16] = f2bf(accO[b2][db][r] * inv);
        }
    }
}

extern "C" void kernel_launch(void* const* d_in, const int* in_sizes, int n_in,
                              void* d_out, int out_size, void* d_ws, size_t ws_size,
                              hipStream_t stream) {
    const float* x   = (const float*)d_in[0];
    const float* w_q = (const float*)d_in[1];
    const float* w_k = (const float*)d_in[2];
    const float* w_v = (const float*)d_in[3];
    const float* w_o = (const float*)d_in[4];
    float* out = (float*)d_out;

    unsigned short* xb  = (unsigned short*)d_ws;
    unsigned short* VtG = xb;                                  // alias: xb dead after QKV gemm
    unsigned short* wqb = xb  + (size_t)MTOT * D_MODEL;
    unsigned short* wkb = wqb + (size_t)D_MODEL * D_MODEL;
    unsigned short* wvb = wkb + (size_t)D_MODEL * D_MODEL;
    unsigned short* wob = wvb + (size_t)D_MODEL * D_MODEL;
    unsigned short* Qb  = wob + (size_t)D_MODEL * D_MODEL;
    unsigned short* Kb  = Qb  + (size_t)MTOT * D_MODEL;
    unsigned short* Vb  = Kb  + (size_t)MTOT * D_MODEL;
    unsigned short* Ab  = Vb  + (size_t)MTOT * D_MODEL;

    dim3 blk(256);
    cvt_all<<<dim3(2048 + 4 * 512), blk, 0, stream>>>(
        x, w_q, w_k, w_v, w_o, xb, wqb, wkb, wvb, wob);
    gemm_bt<false><<<dim3(MTOT / 128, D_MODEL / 128, 3), blk, 0, stream>>>(
        xb, wqb, wkb, wvb, Qb, Kb, Vb, MTOT, D_MODEL, D_MODEL, 0.125f);
    vtrans_kernel<<<dim3(SEQ / 64, BATCH * NHEADS), blk, 0, stream>>>(Vb, VtG);
    attn_kernel<<<dim3(BATCH * NHEADS, 16), blk, 0, stream>>>(Qb, Kb, VtG, Ab);
    gemm_bt<true><<<dim3(MTOT / 128, D_MODEL / 128, 1), blk, 0, stream>>>(
        Ab, wob, wob, wob, out, out, out, MTOT, D_MODEL, D_MODEL, 1.0f);
}